// Round 14
// baseline (402.027 us; speedup 1.0000x reference)
//
#include <hip/hip_runtime.h>
#include <cstdint>
#include <cstddef>

// Extractor_N2V folded: g = seg_sum(h[src],dst)/deg + eps1*h  (bf16 storage)
// BN stats via y = g@W1^T MFMA pass reduced to per-channel sum/sumsq;
// out = g @ M^T + c with M = W2 diag(s) W1 (bf16). CSR via bucket sort.
// R14: k_bfill = LDS counting-sort + burst chunk copy (kills write-allocate
// amp); k_bsort stages pairs in LDS (one global read).

#define IN_DIM 128
#define H_DIM 256
#define NPB 256
#define MAXB 1792
#define FB_CAP 13312
#define BS_CAP 10240

typedef unsigned int uint32;
typedef unsigned short ushort;
typedef __attribute__((ext_vector_type(8))) short short8;
typedef __attribute__((ext_vector_type(4))) float f32x4;
typedef __attribute__((ext_vector_type(4))) uint32 u32x4;

union U16B { uint4 u; short8 s; };

static inline size_t align256(size_t x){ return (x + 255) & ~(size_t)255; }

__device__ inline uint32 f2bf(float f){
  uint32 u = __float_as_uint(f);
  return (u + 0x7FFFu + ((u >> 16) & 1u)) >> 16;   // RNE
}
__device__ inline float bflo(uint32 u){ return __uint_as_float(u << 16); }
__device__ inline float bfhi(uint32 u){ return __uint_as_float(u & 0xFFFF0000u); }

// ---- fused: h->hb (bf16), W1->W1b (bf16), bucket histogram (dst>>8)
__global__ __launch_bounds__(256) void k_prep(const float* __restrict__ h,
                        uint32* __restrict__ hb2, int n4,
                        const float* __restrict__ W1, uint32* __restrict__ W1b2,
                        const int* __restrict__ dst, int* __restrict__ gcount,
                        int E_, int B_) {
  __shared__ int lc[512];
  int t = threadIdx.x;
  int stride = gridDim.x*256;
  for (int i = blockIdx.x*256 + t; i < n4; i += stride) {
    u32x4 uv = __builtin_nontemporal_load((const u32x4*)h + i);
    uint32 lo = f2bf(__uint_as_float(uv.x)) | (f2bf(__uint_as_float(uv.y)) << 16);
    uint32 hi = f2bf(__uint_as_float(uv.z)) | (f2bf(__uint_as_float(uv.w)) << 16);
    ((uint2*)hb2)[i] = make_uint2(lo, hi);
  }
  for (int i = blockIdx.x*256 + t; i < 256*128/4; i += stride) {
    u32x4 uv = *((const u32x4*)W1 + i);
    uint32 lo = f2bf(__uint_as_float(uv.x)) | (f2bf(__uint_as_float(uv.y)) << 16);
    uint32 hi = f2bf(__uint_as_float(uv.z)) | (f2bf(__uint_as_float(uv.w)) << 16);
    ((uint2*)W1b2)[i] = make_uint2(lo, hi);
  }
  for (int j = t; j < B_; j += 256) lc[j] = 0;
  __syncthreads();
  int per = (E_ + gridDim.x - 1) / gridDim.x;
  int beg = blockIdx.x * per, end = min(beg + per, E_);
  for (int j = beg + t; j < end; j += 256)
    atomicAdd(&lc[__builtin_nontemporal_load(dst + j) >> 8], 1);
  __syncthreads();
  for (int j = t; j < B_; j += 256) { int v = lc[j]; if (v) atomicAdd(&gcount[j], v); }
}

// ---- exclusive scan of bucket counts
__global__ __launch_bounds__(256) void k_bscan(const int* __restrict__ gcount,
                        int* __restrict__ boff, int* __restrict__ gcursor,
                        int* __restrict__ row_ptr, int B_, int N_) {
  __shared__ int part[256];
  __shared__ int vals[MAXB];
  int t = threadIdx.x;
  int base = t * 7;
  int s = 0;
  #pragma unroll
  for (int k = 0; k < 7; k++) {
    int idx = base + k;
    int v = (idx < B_) ? gcount[idx] : 0;
    vals[idx < MAXB ? idx : MAXB-1] = s;
    s += v;
  }
  part[t] = s;
  __syncthreads();
  for (int off = 1; off < 256; off <<= 1) {
    int a = (t >= off) ? part[t - off] : 0;
    __syncthreads();
    part[t] += a;
    __syncthreads();
  }
  int pbase = (t > 0) ? part[t - 1] : 0;
  #pragma unroll
  for (int k = 0; k < 7; k++) {
    int idx = base + k;
    if (idx < B_) { int o = pbase + vals[idx]; boff[idx] = o; gcursor[idx] = o; }
  }
  if (t == 255) { boff[B_] = part[255]; row_ptr[N_] = part[255]; }
}

// ---- LDS counting-sort scatter: local sort, reserve chunk, burst copy
__global__ __launch_bounds__(256) void k_bfill(const int* __restrict__ src,
                        const int* __restrict__ dst, int* __restrict__ gcursor,
                        uint32* __restrict__ pairs, int E_, int B_) {
  __shared__ uint32 sbuf[FB_CAP];
  __shared__ int lcnt[512];
  __shared__ int loff[512];
  __shared__ int lcur[512];
  __shared__ int gbase[512];
  __shared__ int part[256];
  int t = threadIdx.x;
  for (int i = t; i < 512; i += 256) lcnt[i] = 0;
  __syncthreads();
  int per = (E_ + gridDim.x - 1) / gridDim.x;
  int beg = blockIdx.x * per, end = min(beg + per, E_);
  for (int i = beg + t; i < end; i += 256)
    atomicAdd(&lcnt[__builtin_nontemporal_load(dst + i) >> 8], 1);
  __syncthreads();
  int v0 = lcnt[t*2], v1 = lcnt[t*2 + 1];
  part[t] = v0 + v1;
  __syncthreads();
  for (int off = 1; off < 256; off <<= 1) {
    int a = (t >= off) ? part[t - off] : 0;
    __syncthreads();
    part[t] += a;
    __syncthreads();
  }
  int pb = (t > 0) ? part[t - 1] : 0;
  loff[t*2] = pb;       lcur[t*2] = pb;
  loff[t*2+1] = pb + v0; lcur[t*2+1] = pb + v0;
  __syncthreads();
  for (int i = beg + t; i < end; i += 256) {
    int d = dst[i];
    int bk = d >> 8;
    int p = atomicAdd(&lcur[bk], 1);
    if (p < FB_CAP) sbuf[p] = (uint32)src[i] | ((uint32)(d & 255) << 20);
  }
  __syncthreads();
  for (int bk = t; bk < B_; bk += 256) {
    int c = lcnt[bk];
    gbase[bk] = c ? atomicAdd(&gcursor[bk], c) : 0;
  }
  __syncthreads();
  int wv = t >> 6, lane = t & 63;
  int bpw = (B_ + 3) >> 2;
  int b0 = wv * bpw, b1 = min(b0 + bpw, B_);
  for (int bk = b0; bk < b1; bk++) {
    int c = lcnt[bk];
    int gb = gbase[bk];
    int lo = loff[bk];
    for (int i = lane; i < c; i += 64)
      pairs[gb + i] = sbuf[lo + i];
  }
}

// ---- per-bucket counting sort -> CSR (512 threads, LDS-staged pairs)
__global__ __launch_bounds__(512) void k_bsort(const uint32* __restrict__ pairs,
                        const int* __restrict__ boff, int* __restrict__ row_ptr,
                        int* __restrict__ eidx, int N_) {
  __shared__ uint32 sb[BS_CAP];
  __shared__ int cnt[256];
  __shared__ int scan[256];
  __shared__ int cursor[256];
  int t = threadIdx.x, b = blockIdx.x;
  if (t < 256) cnt[t] = 0;
  __syncthreads();
  int beg = boff[b], end = boff[b + 1];
  int n = end - beg;
  for (int i = t; i < n; i += 512) {
    uint32 pk = pairs[beg + i];
    if (i < BS_CAP) sb[i] = pk;
    atomicAdd(&cnt[pk >> 20], 1);
  }
  __syncthreads();
  int v = (t < 256) ? cnt[t] : 0;
  if (t < 256) scan[t] = v;
  __syncthreads();
  for (int off = 1; off < 256; off <<= 1) {
    int a = (t >= off && t < 256) ? scan[t - off] : 0;
    __syncthreads();
    if (t < 256) scan[t] += a;
    __syncthreads();
  }
  if (t < 256) {
    int ex = scan[t] - v;
    cursor[t] = ex;
    int node = b * NPB + t;
    if (node < N_) row_ptr[node] = beg + ex;
  }
  __syncthreads();
  for (int i = t; i < n; i += 512) {
    uint32 pk = (i < BS_CAP) ? sb[i] : pairs[beg + i];
    int j = pk >> 20;
    int p = atomicAdd(&cursor[j], 1);
    eidx[beg + p] = (int)(pk & 0xFFFFF);
  }
}

// ---- one wave per node over [n0,n1), 4-deep MLP, nontemporal index loads
__global__ __launch_bounds__(256) void k_gather(const uint32* __restrict__ hb,
                        const int* __restrict__ row_ptr, const int* __restrict__ eidx,
                        const float* __restrict__ eps1, uint32* __restrict__ gb,
                        int n0, int n1) {
  int w = n0 + (int)((blockIdx.x*blockDim.x + threadIdx.x) >> 6);
  w = __builtin_amdgcn_readfirstlane(w);
  int lane = threadIdx.x & 63;
  if (w >= n1) return;
  int beg = __builtin_nontemporal_load(row_ptr + w);
  int end = __builtin_nontemporal_load(row_ptr + w + 1);
  float2 a0 = {0.f,0.f}, a1 = {0.f,0.f}, a2 = {0.f,0.f}, a3 = {0.f,0.f};
  int e = beg;
  for (; e + 3 < end; e += 4) {
    int s0 = __builtin_nontemporal_load(eidx + e);
    int s1 = __builtin_nontemporal_load(eidx + e + 1);
    int s2 = __builtin_nontemporal_load(eidx + e + 2);
    int s3 = __builtin_nontemporal_load(eidx + e + 3);
    uint32 u0 = hb[(size_t)s0*64 + lane];
    uint32 u1 = hb[(size_t)s1*64 + lane];
    uint32 u2 = hb[(size_t)s2*64 + lane];
    uint32 u3 = hb[(size_t)s3*64 + lane];
    a0.x += bflo(u0); a0.y += bfhi(u0);
    a1.x += bflo(u1); a1.y += bfhi(u1);
    a2.x += bflo(u2); a2.y += bfhi(u2);
    a3.x += bflo(u3); a3.y += bfhi(u3);
  }
  for (; e < end; e++) {
    int s0 = __builtin_nontemporal_load(eidx + e);
    uint32 u0 = hb[(size_t)s0*64 + lane];
    a0.x += bflo(u0); a0.y += bfhi(u0);
  }
  float degf = (float)(end - beg);
  float e1 = eps1[0];
  uint32 hu = hb[(size_t)w*64 + lane];
  float ox = ((a0.x + a1.x) + (a2.x + a3.x)) / degf + e1 * bflo(hu);
  float oy = ((a0.y + a1.y) + (a2.y + a3.y)) / degf + e1 * bfhi(hu);
  gb[(size_t)w*64 + lane] = f2bf(ox) | (f2bf(oy) << 16);
}

// ---- y = g@W1^T via MFMA, reduced in-register to per-block col sum/sumsq
__global__ __launch_bounds__(256) void k_xstat(const uint32* __restrict__ gb,
                     const ushort* __restrict__ W1b, float* __restrict__ yslab, int N_) {
  __shared__ float wsl[4][512];
  int t = threadIdx.x;
  int l = t & 63, w = t >> 6;
  int m0 = blockIdx.x*64 + w*16;
  int lm = l & 15, lq = l >> 4;
  const uint4* gb4 = (const uint4*)gb;
  const uint4* W4  = (const uint4*)W1b;
  int arow = m0 + lm; if (arow > N_-1) arow = N_-1;
  U16B a[4];
  #pragma unroll
  for (int kc=0; kc<4; kc++) a[kc].u = gb4[(size_t)arow*16 + kc*4 + lq];
  f32x4 acc[16];
  #pragma unroll
  for (int nt=0; nt<16; nt++) acc[nt] = (f32x4)0.f;
  #pragma unroll
  for (int nt=0; nt<16; nt++){
    int nrow = nt*16 + lm;
    #pragma unroll
    for (int kc=0; kc<4; kc++){
      U16B b; b.u = W4[(size_t)nrow*16 + kc*4 + lq];
      acc[nt] = __builtin_amdgcn_mfma_f32_16x16x32_bf16(a[kc].s, b.s, acc[nt], 0, 0, 0);
    }
  }
  #pragma unroll
  for (int nt=0; nt<16; nt++){
    float s4 = 0.f, q4 = 0.f;
    #pragma unroll
    for (int r=0; r<4; r++){
      int row = m0 + lq*4 + r;
      if (row < N_) { float v = acc[nt][r]; s4 += v; q4 += v*v; }
    }
    s4 += __shfl_xor(s4, 16, 64); s4 += __shfl_xor(s4, 32, 64);
    q4 += __shfl_xor(q4, 16, 64); q4 += __shfl_xor(q4, 32, 64);
    if (lq == 0) { wsl[w][nt*16+lm] = s4; wsl[w][256+nt*16+lm] = q4; }
  }
  __syncthreads();
  float o0 = wsl[0][t] + wsl[1][t] + wsl[2][t] + wsl[3][t];
  float o1 = wsl[0][256+t] + wsl[1][256+t] + wsl[2][256+t] + wsl[3][256+t];
  yslab[(size_t)blockIdx.x*512 + t] = o0;
  yslab[(size_t)blockIdx.x*512 + 256 + t] = o1;
}

// ---- reduce yslab[nblk][512] -> ysum[512]
__global__ __launch_bounds__(256) void k_yreduce(const float* __restrict__ yslab,
                        float* __restrict__ ysum, int nblk, int per) {
  int i = blockIdx.x*256 + threadIdx.x;
  if (i >= 512) return;
  int k0 = blockIdx.y * per;
  int k1 = min(k0 + per, nblk);
  float s = 0.f;
  for (int k = k0; k < k1; k++) s += yslab[(size_t)k*512 + i];
  atomicAdd(&ysum[i], s);
}

// ---- stats: mean/var of y per channel -> s (scale), c (fused output bias)
__global__ void k_stats2(const float* __restrict__ ysum,
                         const float* __restrict__ W2, const float* __restrict__ b2,
                         const float* __restrict__ gamma, const float* __restrict__ beta,
                         float* __restrict__ sbuf, float* __restrict__ cbuf, int N_) {
  __shared__ float tt[256];
  int t = threadIdx.x;
  float invN = 1.f/(float)N_;
  float mean = ysum[t]*invN;
  float var = ysum[256+t]*invN - mean*mean;
  float s = gamma[t]*rsqrtf(var + 1e-5f);
  sbuf[t] = s;
  tt[t] = beta[t] - mean*s;
  __syncthreads();
  float c = b2[t];
  for (int j=0;j<256;j++) c += tt[j]*W2[(size_t)t*256 + j];
  cbuf[t] = c;
}

// M[k,d] = sum_j W2[k,j]*s[j]*W1[j,d]  -> bf16
__global__ void k_matM(const float* __restrict__ W1, const float* __restrict__ W2,
                       const float* __restrict__ sbuf, ushort* __restrict__ Mb) {
  __shared__ float ws[256];
  int k = blockIdx.x, d = threadIdx.x;
  ws[d]       = W2[(size_t)k*256 + d]       * sbuf[d];
  ws[d + 128] = W2[(size_t)k*256 + d + 128] * sbuf[d + 128];
  __syncthreads();
  float acc = 0.f;
  for (int j=0;j<256;j++) acc += ws[j]*W1[(size_t)j*128 + d];
  Mb[(size_t)k*128 + d] = (ushort)f2bf(acc);
}

// ---- out[i,k] = g[i,:].M[k,:] + c[k]  via mfma + LDS-staged coalesced stores
__global__ __launch_bounds__(256) void k_out(const uint32* __restrict__ gb,
                     const ushort* __restrict__ Mb, const float* __restrict__ cb,
                     float* __restrict__ out, int N_) {
  __shared__ float st[4][16][132];
  int t = threadIdx.x;
  int l = t & 63, w = t >> 6;
  int m0 = blockIdx.x*64 + w*16;
  int lm = l & 15, lq = l >> 4;
  const uint4* gb4 = (const uint4*)gb;
  const uint4* Mb4 = (const uint4*)Mb;
  int arow = m0 + lm; if (arow > N_-1) arow = N_-1;
  U16B a[4];
  #pragma unroll
  for (int kc=0; kc<4; kc++) a[kc].u = gb4[(size_t)arow*16 + kc*4 + lq];
  f32x4 acc[16];
  #pragma unroll
  for (int nt=0; nt<16; nt++) acc[nt] = (f32x4)0.f;
  #pragma unroll
  for (int nt=0; nt<16; nt++){
    int nrow = nt*16 + lm;
    #pragma unroll
    for (int kc=0; kc<4; kc++){
      U16B b; b.u = Mb4[(size_t)nrow*16 + kc*4 + lq];
      acc[nt] = __builtin_amdgcn_mfma_f32_16x16x32_bf16(a[kc].s, b.s, acc[nt], 0, 0, 0);
    }
  }
  int rr = l >> 5, cc = l & 31;
  #pragma unroll
  for (int half=0; half<2; half++){
    #pragma unroll
    for (int q8=0; q8<8; q8++){
      int nt = half*8 + q8;
      float cv = cb[nt*16 + lm];
      #pragma unroll
      for (int r=0; r<4; r++)
        st[w][lq*4+r][q8*16+lm] = acc[nt][r] + cv;
    }
    #pragma unroll
    for (int it=0; it<8; it++){
      int row = it*2 + rr;
      int gr = m0 + row;
      float4 v = *(float4*)&st[w][row][cc*4];
      if (gr < N_) *(float4*)&out[(size_t)gr*256 + half*128 + cc*4] = v;
    }
  }
}

extern "C" void kernel_launch(void* const* d_in, const int* in_sizes, int n_in,
                              void* d_out, int out_size, void* d_ws, size_t ws_size,
                              hipStream_t stream) {
  const float* h     = (const float*)d_in[0];
  const int*   esrc  = (const int*)d_in[1];
  const int*   edst  = (const int*)d_in[2];
  const float* W1    = (const float*)d_in[3];
  const float* b1    = (const float*)d_in[4];  (void)b1;
  const float* W2    = (const float*)d_in[5];
  const float* b2    = (const float*)d_in[6];
  const float* gamma = (const float*)d_in[7];
  const float* beta  = (const float*)d_in[8];
  const float* eps1  = (const float*)d_in[9];
  int N = in_sizes[0] / IN_DIM;
  int E = in_sizes[1];
  int B = (N + NPB - 1) / NPB;          // 391 for N=100000
  int nxb = (N + 63) / 64;
  float* out = (float*)d_out;

  char* ws = (char*)d_ws;
  size_t off = 0;
  auto alloc = [&](size_t bytes)->char* {
    char* p = ws + off; off = align256(off + bytes); return p;
  };
  int*    gcount  = (int*)   alloc((size_t)B*4);
  int*    boff    = (int*)   alloc(((size_t)B+1)*4);
  int*    gcursor = (int*)   alloc((size_t)B*4);
  int*    row_ptr = (int*)   alloc(((size_t)N+1)*4);
  uint32* pairs   = (uint32*)alloc((size_t)E*4);
  int*    eidx    = (int*)   alloc((size_t)E*4);
  uint32* hb      = (uint32*)alloc((size_t)N*64*4);
  uint32* gb      = (uint32*)alloc((size_t)N*64*4);
  uint32* W1b     = (uint32*)alloc(256*128*2);
  float*  ysum    = (float*) alloc(512*4);
  float*  yslab   = (float*) alloc((size_t)nxb*512*4);
  float*  sbuf    = (float*) alloc(256*4);
  float*  cbuf    = (float*) alloc(256*4);
  ushort* Mb      = (ushort*)alloc(256*128*2);
  (void)n_in; (void)out_size; (void)ws_size;

  hipMemsetAsync(gcount, 0, (size_t)B*4, stream);
  hipMemsetAsync(ysum, 0, 512*4, stream);

  k_prep  <<<1024, 256, 0, stream>>>(h, hb, N*IN_DIM/4, W1, W1b, edst, gcount, E, B);
  k_bscan <<<1, 256, 0, stream>>>(gcount, boff, gcursor, row_ptr, B, N);
  {
    int fbblk = (E + 12999) / 13000;
    if (fbblk < 256) fbblk = 256;
    k_bfill<<<fbblk, 256, 0, stream>>>(esrc, edst, gcursor, pairs, E, B);
  }
  k_bsort <<<B, 512, 0, stream>>>(pairs, boff, row_ptr, eidx, N);
  {
    int nh = N / 2;
    k_gather<<<(nh+3)/4, 256, 0, stream>>>(hb, row_ptr, eidx, eps1, gb, 0, nh);
    k_gather<<<((N-nh)+3)/4, 256, 0, stream>>>(hb, row_ptr, eidx, eps1, gb, nh, N);
  }
  k_xstat <<<nxb, 256, 0, stream>>>(gb, (const ushort*)W1b, yslab, N);
  {
    int ngrp = 32;
    int per = (nxb + ngrp - 1) / ngrp;
    dim3 rgrid(2, ngrp);
    k_yreduce<<<rgrid, 256, 0, stream>>>(yslab, ysum, nxb, per);
  }
  k_stats2<<<1, 256, 0, stream>>>(ysum, W2, b2, gamma, beta, sbuf, cbuf, N);
  k_matM  <<<256, 128, 0, stream>>>(W1, W2, sbuf, Mb);
  k_out   <<<(N+63)/64, 256, 0, stream>>>(gb, Mb, cbuf, out, N);
}

// Round 15
// 381.483 us; speedup vs baseline: 1.0539x; 1.0539x over previous
//
#include <hip/hip_runtime.h>
#include <cstdint>
#include <cstddef>

// Extractor_N2V folded: g = seg_sum(h[src],dst)/deg + eps1*h  (bf16 storage)
// BN stats via y = g@W1^T MFMA pass reduced to per-channel sum/sumsq;
// out = g @ M^T + c with M = W2 diag(s) W1 (bf16). CSR via bucket sort.
// R15: k_bfill resized: FB_CAP 6400 (35KB LDS -> 4 blk/CU), 512 blocks,
// 16-lane-group burst copy.

#define IN_DIM 128
#define H_DIM 256
#define NPB 256
#define MAXB 1792
#define FB_CAP 6400
#define BS_CAP 10240

typedef unsigned int uint32;
typedef unsigned short ushort;
typedef __attribute__((ext_vector_type(8))) short short8;
typedef __attribute__((ext_vector_type(4))) float f32x4;
typedef __attribute__((ext_vector_type(4))) uint32 u32x4;

union U16B { uint4 u; short8 s; };

static inline size_t align256(size_t x){ return (x + 255) & ~(size_t)255; }

__device__ inline uint32 f2bf(float f){
  uint32 u = __float_as_uint(f);
  return (u + 0x7FFFu + ((u >> 16) & 1u)) >> 16;   // RNE
}
__device__ inline float bflo(uint32 u){ return __uint_as_float(u << 16); }
__device__ inline float bfhi(uint32 u){ return __uint_as_float(u & 0xFFFF0000u); }

// ---- fused: h->hb (bf16), W1->W1b (bf16), bucket histogram (dst>>8)
__global__ __launch_bounds__(256) void k_prep(const float* __restrict__ h,
                        uint32* __restrict__ hb2, int n4,
                        const float* __restrict__ W1, uint32* __restrict__ W1b2,
                        const int* __restrict__ dst, int* __restrict__ gcount,
                        int E_, int B_) {
  __shared__ int lc[512];
  int t = threadIdx.x;
  int stride = gridDim.x*256;
  for (int i = blockIdx.x*256 + t; i < n4; i += stride) {
    u32x4 uv = __builtin_nontemporal_load((const u32x4*)h + i);
    uint32 lo = f2bf(__uint_as_float(uv.x)) | (f2bf(__uint_as_float(uv.y)) << 16);
    uint32 hi = f2bf(__uint_as_float(uv.z)) | (f2bf(__uint_as_float(uv.w)) << 16);
    ((uint2*)hb2)[i] = make_uint2(lo, hi);
  }
  for (int i = blockIdx.x*256 + t; i < 256*128/4; i += stride) {
    u32x4 uv = *((const u32x4*)W1 + i);
    uint32 lo = f2bf(__uint_as_float(uv.x)) | (f2bf(__uint_as_float(uv.y)) << 16);
    uint32 hi = f2bf(__uint_as_float(uv.z)) | (f2bf(__uint_as_float(uv.w)) << 16);
    ((uint2*)W1b2)[i] = make_uint2(lo, hi);
  }
  for (int j = t; j < B_; j += 256) lc[j] = 0;
  __syncthreads();
  int per = (E_ + gridDim.x - 1) / gridDim.x;
  int beg = blockIdx.x * per, end = min(beg + per, E_);
  for (int j = beg + t; j < end; j += 256)
    atomicAdd(&lc[__builtin_nontemporal_load(dst + j) >> 8], 1);
  __syncthreads();
  for (int j = t; j < B_; j += 256) { int v = lc[j]; if (v) atomicAdd(&gcount[j], v); }
}

// ---- exclusive scan of bucket counts
__global__ __launch_bounds__(256) void k_bscan(const int* __restrict__ gcount,
                        int* __restrict__ boff, int* __restrict__ gcursor,
                        int* __restrict__ row_ptr, int B_, int N_) {
  __shared__ int part[256];
  __shared__ int vals[MAXB];
  int t = threadIdx.x;
  int base = t * 7;
  int s = 0;
  #pragma unroll
  for (int k = 0; k < 7; k++) {
    int idx = base + k;
    int v = (idx < B_) ? gcount[idx] : 0;
    vals[idx < MAXB ? idx : MAXB-1] = s;
    s += v;
  }
  part[t] = s;
  __syncthreads();
  for (int off = 1; off < 256; off <<= 1) {
    int a = (t >= off) ? part[t - off] : 0;
    __syncthreads();
    part[t] += a;
    __syncthreads();
  }
  int pbase = (t > 0) ? part[t - 1] : 0;
  #pragma unroll
  for (int k = 0; k < 7; k++) {
    int idx = base + k;
    if (idx < B_) { int o = pbase + vals[idx]; boff[idx] = o; gcursor[idx] = o; }
  }
  if (t == 255) { boff[B_] = part[255]; row_ptr[N_] = part[255]; }
}

// ---- LDS counting-sort scatter: local sort, reserve chunk, burst chunk copy
__global__ __launch_bounds__(256) void k_bfill(const int* __restrict__ src,
                        const int* __restrict__ dst, int* __restrict__ gcursor,
                        uint32* __restrict__ pairs, int E_, int B_) {
  __shared__ uint32 sbuf[FB_CAP];
  __shared__ int lcnt[512];
  __shared__ int loff[512];
  __shared__ int lcur[512];
  __shared__ int gbase[512];
  __shared__ int part[256];
  int t = threadIdx.x;
  for (int i = t; i < 512; i += 256) lcnt[i] = 0;
  __syncthreads();
  int per = (E_ + gridDim.x - 1) / gridDim.x;
  int beg = blockIdx.x * per, end = min(beg + per, E_);
  for (int i = beg + t; i < end; i += 256)
    atomicAdd(&lcnt[__builtin_nontemporal_load(dst + i) >> 8], 1);
  __syncthreads();
  int v0 = lcnt[t*2], v1 = lcnt[t*2 + 1];
  part[t] = v0 + v1;
  __syncthreads();
  for (int off = 1; off < 256; off <<= 1) {
    int a = (t >= off) ? part[t - off] : 0;
    __syncthreads();
    part[t] += a;
    __syncthreads();
  }
  int pb = (t > 0) ? part[t - 1] : 0;
  loff[t*2] = pb;        lcur[t*2] = pb;
  loff[t*2+1] = pb + v0; lcur[t*2+1] = pb + v0;
  __syncthreads();
  for (int i = beg + t; i < end; i += 256) {
    int d = dst[i];
    int bk = d >> 8;
    int p = atomicAdd(&lcur[bk], 1);
    if (p < FB_CAP) sbuf[p] = (uint32)src[i] | ((uint32)(d & 255) << 20);
  }
  __syncthreads();
  for (int bk = t; bk < B_; bk += 256) {
    int c = lcnt[bk];
    gbase[bk] = c ? atomicAdd(&gcursor[bk], c) : 0;
  }
  __syncthreads();
  int grp = t >> 4, gl = t & 15;     // 16 groups of 16 lanes
  for (int bk = grp; bk < B_; bk += 16) {
    int c = lcnt[bk];
    int gb = gbase[bk];
    int lo = loff[bk];
    for (int i = gl; i < c; i += 16)
      pairs[gb + i] = sbuf[lo + i];
  }
}

// ---- per-bucket counting sort -> CSR (512 threads, LDS-staged pairs)
__global__ __launch_bounds__(512) void k_bsort(const uint32* __restrict__ pairs,
                        const int* __restrict__ boff, int* __restrict__ row_ptr,
                        int* __restrict__ eidx, int N_) {
  __shared__ uint32 sb[BS_CAP];
  __shared__ int cnt[256];
  __shared__ int scan[256];
  __shared__ int cursor[256];
  int t = threadIdx.x, b = blockIdx.x;
  if (t < 256) cnt[t] = 0;
  __syncthreads();
  int beg = boff[b], end = boff[b + 1];
  int n = end - beg;
  for (int i = t; i < n; i += 512) {
    uint32 pk = pairs[beg + i];
    if (i < BS_CAP) sb[i] = pk;
    atomicAdd(&cnt[pk >> 20], 1);
  }
  __syncthreads();
  int v = (t < 256) ? cnt[t] : 0;
  if (t < 256) scan[t] = v;
  __syncthreads();
  for (int off = 1; off < 256; off <<= 1) {
    int a = (t >= off && t < 256) ? scan[t - off] : 0;
    __syncthreads();
    if (t < 256) scan[t] += a;
    __syncthreads();
  }
  if (t < 256) {
    int ex = scan[t] - v;
    cursor[t] = ex;
    int node = b * NPB + t;
    if (node < N_) row_ptr[node] = beg + ex;
  }
  __syncthreads();
  for (int i = t; i < n; i += 512) {
    uint32 pk = (i < BS_CAP) ? sb[i] : pairs[beg + i];
    int j = pk >> 20;
    int p = atomicAdd(&cursor[j], 1);
    eidx[beg + p] = (int)(pk & 0xFFFFF);
  }
}

// ---- one wave per node over [n0,n1), 4-deep MLP, nontemporal index loads
__global__ __launch_bounds__(256) void k_gather(const uint32* __restrict__ hb,
                        const int* __restrict__ row_ptr, const int* __restrict__ eidx,
                        const float* __restrict__ eps1, uint32* __restrict__ gb,
                        int n0, int n1) {
  int w = n0 + (int)((blockIdx.x*blockDim.x + threadIdx.x) >> 6);
  w = __builtin_amdgcn_readfirstlane(w);
  int lane = threadIdx.x & 63;
  if (w >= n1) return;
  int beg = __builtin_nontemporal_load(row_ptr + w);
  int end = __builtin_nontemporal_load(row_ptr + w + 1);
  float2 a0 = {0.f,0.f}, a1 = {0.f,0.f}, a2 = {0.f,0.f}, a3 = {0.f,0.f};
  int e = beg;
  for (; e + 3 < end; e += 4) {
    int s0 = __builtin_nontemporal_load(eidx + e);
    int s1 = __builtin_nontemporal_load(eidx + e + 1);
    int s2 = __builtin_nontemporal_load(eidx + e + 2);
    int s3 = __builtin_nontemporal_load(eidx + e + 3);
    uint32 u0 = hb[(size_t)s0*64 + lane];
    uint32 u1 = hb[(size_t)s1*64 + lane];
    uint32 u2 = hb[(size_t)s2*64 + lane];
    uint32 u3 = hb[(size_t)s3*64 + lane];
    a0.x += bflo(u0); a0.y += bfhi(u0);
    a1.x += bflo(u1); a1.y += bfhi(u1);
    a2.x += bflo(u2); a2.y += bfhi(u2);
    a3.x += bflo(u3); a3.y += bfhi(u3);
  }
  for (; e < end; e++) {
    int s0 = __builtin_nontemporal_load(eidx + e);
    uint32 u0 = hb[(size_t)s0*64 + lane];
    a0.x += bflo(u0); a0.y += bfhi(u0);
  }
  float degf = (float)(end - beg);
  float e1 = eps1[0];
  uint32 hu = hb[(size_t)w*64 + lane];
  float ox = ((a0.x + a1.x) + (a2.x + a3.x)) / degf + e1 * bflo(hu);
  float oy = ((a0.y + a1.y) + (a2.y + a3.y)) / degf + e1 * bfhi(hu);
  gb[(size_t)w*64 + lane] = f2bf(ox) | (f2bf(oy) << 16);
}

// ---- y = g@W1^T via MFMA, reduced in-register to per-block col sum/sumsq
__global__ __launch_bounds__(256) void k_xstat(const uint32* __restrict__ gb,
                     const ushort* __restrict__ W1b, float* __restrict__ yslab, int N_) {
  __shared__ float wsl[4][512];
  int t = threadIdx.x;
  int l = t & 63, w = t >> 6;
  int m0 = blockIdx.x*64 + w*16;
  int lm = l & 15, lq = l >> 4;
  const uint4* gb4 = (const uint4*)gb;
  const uint4* W4  = (const uint4*)W1b;
  int arow = m0 + lm; if (arow > N_-1) arow = N_-1;
  U16B a[4];
  #pragma unroll
  for (int kc=0; kc<4; kc++) a[kc].u = gb4[(size_t)arow*16 + kc*4 + lq];
  f32x4 acc[16];
  #pragma unroll
  for (int nt=0; nt<16; nt++) acc[nt] = (f32x4)0.f;
  #pragma unroll
  for (int nt=0; nt<16; nt++){
    int nrow = nt*16 + lm;
    #pragma unroll
    for (int kc=0; kc<4; kc++){
      U16B b; b.u = W4[(size_t)nrow*16 + kc*4 + lq];
      acc[nt] = __builtin_amdgcn_mfma_f32_16x16x32_bf16(a[kc].s, b.s, acc[nt], 0, 0, 0);
    }
  }
  #pragma unroll
  for (int nt=0; nt<16; nt++){
    float s4 = 0.f, q4 = 0.f;
    #pragma unroll
    for (int r=0; r<4; r++){
      int row = m0 + lq*4 + r;
      if (row < N_) { float v = acc[nt][r]; s4 += v; q4 += v*v; }
    }
    s4 += __shfl_xor(s4, 16, 64); s4 += __shfl_xor(s4, 32, 64);
    q4 += __shfl_xor(q4, 16, 64); q4 += __shfl_xor(q4, 32, 64);
    if (lq == 0) { wsl[w][nt*16+lm] = s4; wsl[w][256+nt*16+lm] = q4; }
  }
  __syncthreads();
  float o0 = wsl[0][t] + wsl[1][t] + wsl[2][t] + wsl[3][t];
  float o1 = wsl[0][256+t] + wsl[1][256+t] + wsl[2][256+t] + wsl[3][256+t];
  yslab[(size_t)blockIdx.x*512 + t] = o0;
  yslab[(size_t)blockIdx.x*512 + 256 + t] = o1;
}

// ---- reduce yslab[nblk][512] -> ysum[512]
__global__ __launch_bounds__(256) void k_yreduce(const float* __restrict__ yslab,
                        float* __restrict__ ysum, int nblk, int per) {
  int i = blockIdx.x*256 + threadIdx.x;
  if (i >= 512) return;
  int k0 = blockIdx.y * per;
  int k1 = min(k0 + per, nblk);
  float s = 0.f;
  for (int k = k0; k < k1; k++) s += yslab[(size_t)k*512 + i];
  atomicAdd(&ysum[i], s);
}

// ---- stats: mean/var of y per channel -> s (scale), c (fused output bias)
__global__ void k_stats2(const float* __restrict__ ysum,
                         const float* __restrict__ W2, const float* __restrict__ b2,
                         const float* __restrict__ gamma, const float* __restrict__ beta,
                         float* __restrict__ sbuf, float* __restrict__ cbuf, int N_) {
  __shared__ float tt[256];
  int t = threadIdx.x;
  float invN = 1.f/(float)N_;
  float mean = ysum[t]*invN;
  float var = ysum[256+t]*invN - mean*mean;
  float s = gamma[t]*rsqrtf(var + 1e-5f);
  sbuf[t] = s;
  tt[t] = beta[t] - mean*s;
  __syncthreads();
  float c = b2[t];
  for (int j=0;j<256;j++) c += tt[j]*W2[(size_t)t*256 + j];
  cbuf[t] = c;
}

// M[k,d] = sum_j W2[k,j]*s[j]*W1[j,d]  -> bf16
__global__ void k_matM(const float* __restrict__ W1, const float* __restrict__ W2,
                       const float* __restrict__ sbuf, ushort* __restrict__ Mb) {
  __shared__ float ws[256];
  int k = blockIdx.x, d = threadIdx.x;
  ws[d]       = W2[(size_t)k*256 + d]       * sbuf[d];
  ws[d + 128] = W2[(size_t)k*256 + d + 128] * sbuf[d + 128];
  __syncthreads();
  float acc = 0.f;
  for (int j=0;j<256;j++) acc += ws[j]*W1[(size_t)j*128 + d];
  Mb[(size_t)k*128 + d] = (ushort)f2bf(acc);
}

// ---- out[i,k] = g[i,:].M[k,:] + c[k]  via mfma + LDS-staged coalesced stores
__global__ __launch_bounds__(256) void k_out(const uint32* __restrict__ gb,
                     const ushort* __restrict__ Mb, const float* __restrict__ cb,
                     float* __restrict__ out, int N_) {
  __shared__ float st[4][16][132];
  int t = threadIdx.x;
  int l = t & 63, w = t >> 6;
  int m0 = blockIdx.x*64 + w*16;
  int lm = l & 15, lq = l >> 4;
  const uint4* gb4 = (const uint4*)gb;
  const uint4* Mb4 = (const uint4*)Mb;
  int arow = m0 + lm; if (arow > N_-1) arow = N_-1;
  U16B a[4];
  #pragma unroll
  for (int kc=0; kc<4; kc++) a[kc].u = gb4[(size_t)arow*16 + kc*4 + lq];
  f32x4 acc[16];
  #pragma unroll
  for (int nt=0; nt<16; nt++) acc[nt] = (f32x4)0.f;
  #pragma unroll
  for (int nt=0; nt<16; nt++){
    int nrow = nt*16 + lm;
    #pragma unroll
    for (int kc=0; kc<4; kc++){
      U16B b; b.u = Mb4[(size_t)nrow*16 + kc*4 + lq];
      acc[nt] = __builtin_amdgcn_mfma_f32_16x16x32_bf16(a[kc].s, b.s, acc[nt], 0, 0, 0);
    }
  }
  int rr = l >> 5, cc = l & 31;
  #pragma unroll
  for (int half=0; half<2; half++){
    #pragma unroll
    for (int q8=0; q8<8; q8++){
      int nt = half*8 + q8;
      float cv = cb[nt*16 + lm];
      #pragma unroll
      for (int r=0; r<4; r++)
        st[w][lq*4+r][q8*16+lm] = acc[nt][r] + cv;
    }
    #pragma unroll
    for (int it=0; it<8; it++){
      int row = it*2 + rr;
      int gr = m0 + row;
      float4 v = *(float4*)&st[w][row][cc*4];
      if (gr < N_) *(float4*)&out[(size_t)gr*256 + half*128 + cc*4] = v;
    }
  }
}

extern "C" void kernel_launch(void* const* d_in, const int* in_sizes, int n_in,
                              void* d_out, int out_size, void* d_ws, size_t ws_size,
                              hipStream_t stream) {
  const float* h     = (const float*)d_in[0];
  const int*   esrc  = (const int*)d_in[1];
  const int*   edst  = (const int*)d_in[2];
  const float* W1    = (const float*)d_in[3];
  const float* b1    = (const float*)d_in[4];  (void)b1;
  const float* W2    = (const float*)d_in[5];
  const float* b2    = (const float*)d_in[6];
  const float* gamma = (const float*)d_in[7];
  const float* beta  = (const float*)d_in[8];
  const float* eps1  = (const float*)d_in[9];
  int N = in_sizes[0] / IN_DIM;
  int E = in_sizes[1];
  int B = (N + NPB - 1) / NPB;          // 391 for N=100000
  int nxb = (N + 63) / 64;
  float* out = (float*)d_out;

  char* ws = (char*)d_ws;
  size_t off = 0;
  auto alloc = [&](size_t bytes)->char* {
    char* p = ws + off; off = align256(off + bytes); return p;
  };
  int*    gcount  = (int*)   alloc((size_t)B*4);
  int*    boff    = (int*)   alloc(((size_t)B+1)*4);
  int*    gcursor = (int*)   alloc((size_t)B*4);
  int*    row_ptr = (int*)   alloc(((size_t)N+1)*4);
  uint32* pairs   = (uint32*)alloc((size_t)E*4);
  int*    eidx    = (int*)   alloc((size_t)E*4);
  uint32* hb      = (uint32*)alloc((size_t)N*64*4);
  uint32* gb      = (uint32*)alloc((size_t)N*64*4);
  uint32* W1b     = (uint32*)alloc(256*128*2);
  float*  ysum    = (float*) alloc(512*4);
  float*  yslab   = (float*) alloc((size_t)nxb*512*4);
  float*  sbuf    = (float*) alloc(256*4);
  float*  cbuf    = (float*) alloc(256*4);
  ushort* Mb      = (ushort*)alloc(256*128*2);
  (void)n_in; (void)out_size; (void)ws_size;

  hipMemsetAsync(gcount, 0, (size_t)B*4, stream);
  hipMemsetAsync(ysum, 0, 512*4, stream);

  k_prep  <<<1024, 256, 0, stream>>>(h, hb, N*IN_DIM/4, W1, W1b, edst, gcount, E, B);
  k_bscan <<<1, 256, 0, stream>>>(gcount, boff, gcursor, row_ptr, B, N);
  {
    int fbblk = (E + FB_CAP - 101) / (FB_CAP - 100);   // per-block <= FB_CAP-ish
    if (fbblk < 512) fbblk = 512;
    k_bfill<<<fbblk, 256, 0, stream>>>(esrc, edst, gcursor, pairs, E, B);
  }
  k_bsort <<<B, 512, 0, stream>>>(pairs, boff, row_ptr, eidx, N);
  {
    int nh = N / 2;
    k_gather<<<(nh+3)/4, 256, 0, stream>>>(hb, row_ptr, eidx, eps1, gb, 0, nh);
    k_gather<<<((N-nh)+3)/4, 256, 0, stream>>>(hb, row_ptr, eidx, eps1, gb, nh, N);
  }
  k_xstat <<<nxb, 256, 0, stream>>>(gb, (const ushort*)W1b, yslab, N);
  {
    int ngrp = 32;
    int per = (nxb + ngrp - 1) / ngrp;
    dim3 rgrid(2, ngrp);
    k_yreduce<<<rgrid, 256, 0, stream>>>(yslab, ysum, nxb, per);
  }
  k_stats2<<<1, 256, 0, stream>>>(ysum, W2, b2, gamma, beta, sbuf, cbuf, N);
  k_matM  <<<256, 128, 0, stream>>>(W1, W2, sbuf, Mb);
  k_out   <<<(N+63)/64, 256, 0, stream>>>(gb, Mb, cbuf, out, N);
}

// Round 16
// 380.869 us; speedup vs baseline: 1.0556x; 1.0016x over previous
//
#include <hip/hip_runtime.h>
#include <cstdint>
#include <cstddef>

// Extractor_N2V folded: g = seg_sum(h[src],dst)/deg + eps1*h  (bf16 storage)
// BN stats via y = g@W1^T MFMA pass reduced to per-channel sum/sumsq;
// out = g @ M^T + c with M = W2 diag(s) W1 (bf16). CSR via bucket sort.
// R16: k_out quarter-staged (17KB LDS -> 8 blk/CU, one occupancy round) +
// nontemporal f32x4 output stores.

#define IN_DIM 128
#define H_DIM 256
#define NPB 256
#define MAXB 1792
#define FB_CAP 6400
#define BS_CAP 10240

typedef unsigned int uint32;
typedef unsigned short ushort;
typedef __attribute__((ext_vector_type(8))) short short8;
typedef __attribute__((ext_vector_type(4))) float f32x4;
typedef __attribute__((ext_vector_type(4))) uint32 u32x4;

union U16B { uint4 u; short8 s; };

static inline size_t align256(size_t x){ return (x + 255) & ~(size_t)255; }

__device__ inline uint32 f2bf(float f){
  uint32 u = __float_as_uint(f);
  return (u + 0x7FFFu + ((u >> 16) & 1u)) >> 16;   // RNE
}
__device__ inline float bflo(uint32 u){ return __uint_as_float(u << 16); }
__device__ inline float bfhi(uint32 u){ return __uint_as_float(u & 0xFFFF0000u); }

// ---- fused: h->hb (bf16), W1->W1b (bf16), bucket histogram (dst>>8)
__global__ __launch_bounds__(256) void k_prep(const float* __restrict__ h,
                        uint32* __restrict__ hb2, int n4,
                        const float* __restrict__ W1, uint32* __restrict__ W1b2,
                        const int* __restrict__ dst, int* __restrict__ gcount,
                        int E_, int B_) {
  __shared__ int lc[512];
  int t = threadIdx.x;
  int stride = gridDim.x*256;
  for (int i = blockIdx.x*256 + t; i < n4; i += stride) {
    u32x4 uv = __builtin_nontemporal_load((const u32x4*)h + i);
    uint32 lo = f2bf(__uint_as_float(uv.x)) | (f2bf(__uint_as_float(uv.y)) << 16);
    uint32 hi = f2bf(__uint_as_float(uv.z)) | (f2bf(__uint_as_float(uv.w)) << 16);
    ((uint2*)hb2)[i] = make_uint2(lo, hi);
  }
  for (int i = blockIdx.x*256 + t; i < 256*128/4; i += stride) {
    u32x4 uv = *((const u32x4*)W1 + i);
    uint32 lo = f2bf(__uint_as_float(uv.x)) | (f2bf(__uint_as_float(uv.y)) << 16);
    uint32 hi = f2bf(__uint_as_float(uv.z)) | (f2bf(__uint_as_float(uv.w)) << 16);
    ((uint2*)W1b2)[i] = make_uint2(lo, hi);
  }
  for (int j = t; j < B_; j += 256) lc[j] = 0;
  __syncthreads();
  int per = (E_ + gridDim.x - 1) / gridDim.x;
  int beg = blockIdx.x * per, end = min(beg + per, E_);
  for (int j = beg + t; j < end; j += 256)
    atomicAdd(&lc[__builtin_nontemporal_load(dst + j) >> 8], 1);
  __syncthreads();
  for (int j = t; j < B_; j += 256) { int v = lc[j]; if (v) atomicAdd(&gcount[j], v); }
}

// ---- exclusive scan of bucket counts
__global__ __launch_bounds__(256) void k_bscan(const int* __restrict__ gcount,
                        int* __restrict__ boff, int* __restrict__ gcursor,
                        int* __restrict__ row_ptr, int B_, int N_) {
  __shared__ int part[256];
  __shared__ int vals[MAXB];
  int t = threadIdx.x;
  int base = t * 7;
  int s = 0;
  #pragma unroll
  for (int k = 0; k < 7; k++) {
    int idx = base + k;
    int v = (idx < B_) ? gcount[idx] : 0;
    vals[idx < MAXB ? idx : MAXB-1] = s;
    s += v;
  }
  part[t] = s;
  __syncthreads();
  for (int off = 1; off < 256; off <<= 1) {
    int a = (t >= off) ? part[t - off] : 0;
    __syncthreads();
    part[t] += a;
    __syncthreads();
  }
  int pbase = (t > 0) ? part[t - 1] : 0;
  #pragma unroll
  for (int k = 0; k < 7; k++) {
    int idx = base + k;
    if (idx < B_) { int o = pbase + vals[idx]; boff[idx] = o; gcursor[idx] = o; }
  }
  if (t == 255) { boff[B_] = part[255]; row_ptr[N_] = part[255]; }
}

// ---- LDS counting-sort scatter: local sort, reserve chunk, burst chunk copy
__global__ __launch_bounds__(256) void k_bfill(const int* __restrict__ src,
                        const int* __restrict__ dst, int* __restrict__ gcursor,
                        uint32* __restrict__ pairs, int E_, int B_) {
  __shared__ uint32 sbuf[FB_CAP];
  __shared__ int lcnt[512];
  __shared__ int loff[512];
  __shared__ int lcur[512];
  __shared__ int gbase[512];
  __shared__ int part[256];
  int t = threadIdx.x;
  for (int i = t; i < 512; i += 256) lcnt[i] = 0;
  __syncthreads();
  int per = (E_ + gridDim.x - 1) / gridDim.x;
  int beg = blockIdx.x * per, end = min(beg + per, E_);
  for (int i = beg + t; i < end; i += 256)
    atomicAdd(&lcnt[__builtin_nontemporal_load(dst + i) >> 8], 1);
  __syncthreads();
  int v0 = lcnt[t*2], v1 = lcnt[t*2 + 1];
  part[t] = v0 + v1;
  __syncthreads();
  for (int off = 1; off < 256; off <<= 1) {
    int a = (t >= off) ? part[t - off] : 0;
    __syncthreads();
    part[t] += a;
    __syncthreads();
  }
  int pb = (t > 0) ? part[t - 1] : 0;
  loff[t*2] = pb;        lcur[t*2] = pb;
  loff[t*2+1] = pb + v0; lcur[t*2+1] = pb + v0;
  __syncthreads();
  for (int i = beg + t; i < end; i += 256) {
    int d = dst[i];
    int bk = d >> 8;
    int p = atomicAdd(&lcur[bk], 1);
    if (p < FB_CAP) sbuf[p] = (uint32)src[i] | ((uint32)(d & 255) << 20);
  }
  __syncthreads();
  for (int bk = t; bk < B_; bk += 256) {
    int c = lcnt[bk];
    gbase[bk] = c ? atomicAdd(&gcursor[bk], c) : 0;
  }
  __syncthreads();
  int grp = t >> 4, gl = t & 15;     // 16 groups of 16 lanes
  for (int bk = grp; bk < B_; bk += 16) {
    int c = lcnt[bk];
    int gb = gbase[bk];
    int lo = loff[bk];
    for (int i = gl; i < c; i += 16)
      pairs[gb + i] = sbuf[lo + i];
  }
}

// ---- per-bucket counting sort -> CSR (512 threads, LDS-staged pairs)
__global__ __launch_bounds__(512) void k_bsort(const uint32* __restrict__ pairs,
                        const int* __restrict__ boff, int* __restrict__ row_ptr,
                        int* __restrict__ eidx, int N_) {
  __shared__ uint32 sb[BS_CAP];
  __shared__ int cnt[256];
  __shared__ int scan[256];
  __shared__ int cursor[256];
  int t = threadIdx.x, b = blockIdx.x;
  if (t < 256) cnt[t] = 0;
  __syncthreads();
  int beg = boff[b], end = boff[b + 1];
  int n = end - beg;
  for (int i = t; i < n; i += 512) {
    uint32 pk = pairs[beg + i];
    if (i < BS_CAP) sb[i] = pk;
    atomicAdd(&cnt[pk >> 20], 1);
  }
  __syncthreads();
  int v = (t < 256) ? cnt[t] : 0;
  if (t < 256) scan[t] = v;
  __syncthreads();
  for (int off = 1; off < 256; off <<= 1) {
    int a = (t >= off && t < 256) ? scan[t - off] : 0;
    __syncthreads();
    if (t < 256) scan[t] += a;
    __syncthreads();
  }
  if (t < 256) {
    int ex = scan[t] - v;
    cursor[t] = ex;
    int node = b * NPB + t;
    if (node < N_) row_ptr[node] = beg + ex;
  }
  __syncthreads();
  for (int i = t; i < n; i += 512) {
    uint32 pk = (i < BS_CAP) ? sb[i] : pairs[beg + i];
    int j = pk >> 20;
    int p = atomicAdd(&cursor[j], 1);
    eidx[beg + p] = (int)(pk & 0xFFFFF);
  }
}

// ---- one wave per node over [n0,n1), 4-deep MLP, nontemporal index loads
__global__ __launch_bounds__(256) void k_gather(const uint32* __restrict__ hb,
                        const int* __restrict__ row_ptr, const int* __restrict__ eidx,
                        const float* __restrict__ eps1, uint32* __restrict__ gb,
                        int n0, int n1) {
  int w = n0 + (int)((blockIdx.x*blockDim.x + threadIdx.x) >> 6);
  w = __builtin_amdgcn_readfirstlane(w);
  int lane = threadIdx.x & 63;
  if (w >= n1) return;
  int beg = __builtin_nontemporal_load(row_ptr + w);
  int end = __builtin_nontemporal_load(row_ptr + w + 1);
  float2 a0 = {0.f,0.f}, a1 = {0.f,0.f}, a2 = {0.f,0.f}, a3 = {0.f,0.f};
  int e = beg;
  for (; e + 3 < end; e += 4) {
    int s0 = __builtin_nontemporal_load(eidx + e);
    int s1 = __builtin_nontemporal_load(eidx + e + 1);
    int s2 = __builtin_nontemporal_load(eidx + e + 2);
    int s3 = __builtin_nontemporal_load(eidx + e + 3);
    uint32 u0 = hb[(size_t)s0*64 + lane];
    uint32 u1 = hb[(size_t)s1*64 + lane];
    uint32 u2 = hb[(size_t)s2*64 + lane];
    uint32 u3 = hb[(size_t)s3*64 + lane];
    a0.x += bflo(u0); a0.y += bfhi(u0);
    a1.x += bflo(u1); a1.y += bfhi(u1);
    a2.x += bflo(u2); a2.y += bfhi(u2);
    a3.x += bflo(u3); a3.y += bfhi(u3);
  }
  for (; e < end; e++) {
    int s0 = __builtin_nontemporal_load(eidx + e);
    uint32 u0 = hb[(size_t)s0*64 + lane];
    a0.x += bflo(u0); a0.y += bfhi(u0);
  }
  float degf = (float)(end - beg);
  float e1 = eps1[0];
  uint32 hu = hb[(size_t)w*64 + lane];
  float ox = ((a0.x + a1.x) + (a2.x + a3.x)) / degf + e1 * bflo(hu);
  float oy = ((a0.y + a1.y) + (a2.y + a3.y)) / degf + e1 * bfhi(hu);
  gb[(size_t)w*64 + lane] = f2bf(ox) | (f2bf(oy) << 16);
}

// ---- y = g@W1^T via MFMA, reduced in-register to per-block col sum/sumsq
__global__ __launch_bounds__(256) void k_xstat(const uint32* __restrict__ gb,
                     const ushort* __restrict__ W1b, float* __restrict__ yslab, int N_) {
  __shared__ float wsl[4][512];
  int t = threadIdx.x;
  int l = t & 63, w = t >> 6;
  int m0 = blockIdx.x*64 + w*16;
  int lm = l & 15, lq = l >> 4;
  const uint4* gb4 = (const uint4*)gb;
  const uint4* W4  = (const uint4*)W1b;
  int arow = m0 + lm; if (arow > N_-1) arow = N_-1;
  U16B a[4];
  #pragma unroll
  for (int kc=0; kc<4; kc++) a[kc].u = gb4[(size_t)arow*16 + kc*4 + lq];
  f32x4 acc[16];
  #pragma unroll
  for (int nt=0; nt<16; nt++) acc[nt] = (f32x4)0.f;
  #pragma unroll
  for (int nt=0; nt<16; nt++){
    int nrow = nt*16 + lm;
    #pragma unroll
    for (int kc=0; kc<4; kc++){
      U16B b; b.u = W4[(size_t)nrow*16 + kc*4 + lq];
      acc[nt] = __builtin_amdgcn_mfma_f32_16x16x32_bf16(a[kc].s, b.s, acc[nt], 0, 0, 0);
    }
  }
  #pragma unroll
  for (int nt=0; nt<16; nt++){
    float s4 = 0.f, q4 = 0.f;
    #pragma unroll
    for (int r=0; r<4; r++){
      int row = m0 + lq*4 + r;
      if (row < N_) { float v = acc[nt][r]; s4 += v; q4 += v*v; }
    }
    s4 += __shfl_xor(s4, 16, 64); s4 += __shfl_xor(s4, 32, 64);
    q4 += __shfl_xor(q4, 16, 64); q4 += __shfl_xor(q4, 32, 64);
    if (lq == 0) { wsl[w][nt*16+lm] = s4; wsl[w][256+nt*16+lm] = q4; }
  }
  __syncthreads();
  float o0 = wsl[0][t] + wsl[1][t] + wsl[2][t] + wsl[3][t];
  float o1 = wsl[0][256+t] + wsl[1][256+t] + wsl[2][256+t] + wsl[3][256+t];
  yslab[(size_t)blockIdx.x*512 + t] = o0;
  yslab[(size_t)blockIdx.x*512 + 256 + t] = o1;
}

// ---- reduce yslab[nblk][512] -> ysum[512]
__global__ __launch_bounds__(256) void k_yreduce(const float* __restrict__ yslab,
                        float* __restrict__ ysum, int nblk, int per) {
  int i = blockIdx.x*256 + threadIdx.x;
  if (i >= 512) return;
  int k0 = blockIdx.y * per;
  int k1 = min(k0 + per, nblk);
  float s = 0.f;
  for (int k = k0; k < k1; k++) s += yslab[(size_t)k*512 + i];
  atomicAdd(&ysum[i], s);
}

// ---- stats: mean/var of y per channel -> s (scale), c (fused output bias)
__global__ void k_stats2(const float* __restrict__ ysum,
                         const float* __restrict__ W2, const float* __restrict__ b2,
                         const float* __restrict__ gamma, const float* __restrict__ beta,
                         float* __restrict__ sbuf, float* __restrict__ cbuf, int N_) {
  __shared__ float tt[256];
  int t = threadIdx.x;
  float invN = 1.f/(float)N_;
  float mean = ysum[t]*invN;
  float var = ysum[256+t]*invN - mean*mean;
  float s = gamma[t]*rsqrtf(var + 1e-5f);
  sbuf[t] = s;
  tt[t] = beta[t] - mean*s;
  __syncthreads();
  float c = b2[t];
  for (int j=0;j<256;j++) c += tt[j]*W2[(size_t)t*256 + j];
  cbuf[t] = c;
}

// M[k,d] = sum_j W2[k,j]*s[j]*W1[j,d]  -> bf16
__global__ void k_matM(const float* __restrict__ W1, const float* __restrict__ W2,
                       const float* __restrict__ sbuf, ushort* __restrict__ Mb) {
  __shared__ float ws[256];
  int k = blockIdx.x, d = threadIdx.x;
  ws[d]       = W2[(size_t)k*256 + d]       * sbuf[d];
  ws[d + 128] = W2[(size_t)k*256 + d + 128] * sbuf[d + 128];
  __syncthreads();
  float acc = 0.f;
  for (int j=0;j<256;j++) acc += ws[j]*W1[(size_t)j*128 + d];
  Mb[(size_t)k*128 + d] = (ushort)f2bf(acc);
}

// ---- out[i,k] = g[i,:].M[k,:] + c[k]  via mfma + quarter-staged LDS + nt stores
__global__ __launch_bounds__(256) void k_out(const uint32* __restrict__ gb,
                     const ushort* __restrict__ Mb, const float* __restrict__ cb,
                     float* __restrict__ out, int N_) {
  __shared__ float st[4][16][68];
  int t = threadIdx.x;
  int l = t & 63, w = t >> 6;
  int m0 = blockIdx.x*64 + w*16;
  int lm = l & 15, lq = l >> 4;
  const uint4* gb4 = (const uint4*)gb;
  const uint4* Mb4 = (const uint4*)Mb;
  int arow = m0 + lm; if (arow > N_-1) arow = N_-1;
  U16B a[4];
  #pragma unroll
  for (int kc=0; kc<4; kc++) a[kc].u = gb4[(size_t)arow*16 + kc*4 + lq];
  f32x4 acc[16];
  #pragma unroll
  for (int nt=0; nt<16; nt++) acc[nt] = (f32x4)0.f;
  #pragma unroll
  for (int nt=0; nt<16; nt++){
    int nrow = nt*16 + lm;
    #pragma unroll
    for (int kc=0; kc<4; kc++){
      U16B b; b.u = Mb4[(size_t)nrow*16 + kc*4 + lq];
      acc[nt] = __builtin_amdgcn_mfma_f32_16x16x32_bf16(a[kc].s, b.s, acc[nt], 0, 0, 0);
    }
  }
  // epilogue: 4 quarters of 64 cols; stage in 17KB LDS, nt-stream out
  #pragma unroll
  for (int q=0; q<4; q++){
    #pragma unroll
    for (int j=0; j<4; j++){
      int nt = q*4 + j;
      float cv = cb[nt*16 + lm];
      #pragma unroll
      for (int r=0; r<4; r++)
        st[w][lq*4+r][j*16+lm] = acc[nt][r] + cv;
    }
    // same-wave LDS ordering: write then read, in-order per wave
    #pragma unroll
    for (int it=0; it<4; it++){
      int row = it*4 + lq;
      int gr = m0 + row;
      f32x4 v = *(f32x4*)&st[w][row][lm*4];
      if (gr < N_)
        __builtin_nontemporal_store(v, (f32x4*)&out[(size_t)gr*256 + q*64 + lm*4]);
    }
  }
}

extern "C" void kernel_launch(void* const* d_in, const int* in_sizes, int n_in,
                              void* d_out, int out_size, void* d_ws, size_t ws_size,
                              hipStream_t stream) {
  const float* h     = (const float*)d_in[0];
  const int*   esrc  = (const int*)d_in[1];
  const int*   edst  = (const int*)d_in[2];
  const float* W1    = (const float*)d_in[3];
  const float* b1    = (const float*)d_in[4];  (void)b1;
  const float* W2    = (const float*)d_in[5];
  const float* b2    = (const float*)d_in[6];
  const float* gamma = (const float*)d_in[7];
  const float* beta  = (const float*)d_in[8];
  const float* eps1  = (const float*)d_in[9];
  int N = in_sizes[0] / IN_DIM;
  int E = in_sizes[1];
  int B = (N + NPB - 1) / NPB;          // 391 for N=100000
  int nxb = (N + 63) / 64;
  float* out = (float*)d_out;

  char* ws = (char*)d_ws;
  size_t off = 0;
  auto alloc = [&](size_t bytes)->char* {
    char* p = ws + off; off = align256(off + bytes); return p;
  };
  int*    gcount  = (int*)   alloc((size_t)B*4);
  int*    boff    = (int*)   alloc(((size_t)B+1)*4);
  int*    gcursor = (int*)   alloc((size_t)B*4);
  int*    row_ptr = (int*)   alloc(((size_t)N+1)*4);
  uint32* pairs   = (uint32*)alloc((size_t)E*4);
  int*    eidx    = (int*)   alloc((size_t)E*4);
  uint32* hb      = (uint32*)alloc((size_t)N*64*4);
  uint32* gb      = (uint32*)alloc((size_t)N*64*4);
  uint32* W1b     = (uint32*)alloc(256*128*2);
  float*  ysum    = (float*) alloc(512*4);
  float*  yslab   = (float*) alloc((size_t)nxb*512*4);
  float*  sbuf    = (float*) alloc(256*4);
  float*  cbuf    = (float*) alloc(256*4);
  ushort* Mb      = (ushort*)alloc(256*128*2);
  (void)n_in; (void)out_size; (void)ws_size;

  hipMemsetAsync(gcount, 0, (size_t)B*4, stream);
  hipMemsetAsync(ysum, 0, 512*4, stream);

  k_prep  <<<1024, 256, 0, stream>>>(h, hb, N*IN_DIM/4, W1, W1b, edst, gcount, E, B);
  k_bscan <<<1, 256, 0, stream>>>(gcount, boff, gcursor, row_ptr, B, N);
  {
    int fbblk = (E + FB_CAP - 101) / (FB_CAP - 100);
    if (fbblk < 512) fbblk = 512;
    k_bfill<<<fbblk, 256, 0, stream>>>(esrc, edst, gcursor, pairs, E, B);
  }
  k_bsort <<<B, 512, 0, stream>>>(pairs, boff, row_ptr, eidx, N);
  {
    int nh = N / 2;
    k_gather<<<(nh+3)/4, 256, 0, stream>>>(hb, row_ptr, eidx, eps1, gb, 0, nh);
    k_gather<<<((N-nh)+3)/4, 256, 0, stream>>>(hb, row_ptr, eidx, eps1, gb, nh, N);
  }
  k_xstat <<<nxb, 256, 0, stream>>>(gb, (const ushort*)W1b, yslab, N);
  {
    int ngrp = 32;
    int per = (nxb + ngrp - 1) / ngrp;
    dim3 rgrid(2, ngrp);
    k_yreduce<<<rgrid, 256, 0, stream>>>(yslab, ysum, nxb, per);
  }
  k_stats2<<<1, 256, 0, stream>>>(ysum, W2, b2, gamma, beta, sbuf, cbuf, N);
  k_matM  <<<256, 128, 0, stream>>>(W1, W2, sbuf, Mb);
  k_out   <<<(N+63)/64, 256, 0, stream>>>(gb, Mb, cbuf, out, N);
}